// Round 17
// baseline (23.566 us; speedup 1.0000x reference)
//
#include <hip/hip_runtime.h>
#include <hip/hip_bf16.h>
#include <cstdint>

// B=65536, D=128, H=256, O=8, E=8
// Algebra: no activation between head Linears -> y = h @ (W1 W2) + (b1 W2 + b2).
// Budget (r14/r15): floor ~6.7us | prep+launch ~3.9 | fused+launch ~12.7.
// r17: amortize weight streaming 2x -- each block runs TWO 32-row tiles with
// weights register-resident across both (per-CU memory-path bytes 900->512KB).
// ws layout (weights pre-packed in MFMA FRAGMENT ORDER for coalesced loads):
//   wsP  uint4[4096]  @0      (64KB): wsP[((kg*4+hi)*4+wv)*64+lane] = A-frag of Ws^T
//   wfP  uint4[2048]  @65536  (32KB): wfP[(kg*4+wv)*64+lane]        = B-frag of (W1@W2)^T
//   bfuse f32[64]     @98304:          bfuse[e*8+o] = (b1[e]@W2[e])[o] + b2[e][o]

using bf16x8 = __attribute__((ext_vector_type(8))) __bf16;
using f32x4  = __attribute__((ext_vector_type(4))) float;

__device__ __forceinline__ unsigned short bf16b(float f) {
    __bf16 h = (__bf16)f;                       // RNE; pairs fuse to v_cvt_pk_bf16_f32
    return __builtin_bit_cast(unsigned short, h);
}
__device__ __forceinline__ unsigned pack2(float a, float b) {
    return (unsigned)bf16b(a) | ((unsigned)bf16b(b) << 16);
}

// ---------------------------------------------------------------------------
// Prep v5 (validated r9-r16): 273 blocks.
// ---------------------------------------------------------------------------
__global__ void prep_kernel(const float* __restrict__ Ws,
                            const float* __restrict__ b1,
                            const float* __restrict__ W1,
                            const float* __restrict__ W2,
                            const float* __restrict__ b2,
                            uint4* __restrict__ wsP,
                            unsigned short* __restrict__ wfP,
                            float* __restrict__ bfuse) {
    const int bid = blockIdx.x, tid = threadIdx.x;
    if (bid < 256) {
        __shared__ float w2sT[8][256];               // W2[e]^T : [o][k]
        const int e = bid >> 5, mc = bid & 31;
        const float* W2e = W2 + (size_t)e * 2048;
        float4 v0 = ((const float4*)W2e)[tid];
        float4 v1 = ((const float4*)W2e)[256 + tid];
        const int mloc = tid >> 5, kg = tid & 31;    // k = kg + i*32
        const int m = mc * 8 + mloc;
        const float* w1row = W1 + ((size_t)e * 256 + m) * 256;
        float w1v[8];
        #pragma unroll
        for (int i = 0; i < 8; ++i) w1v[i] = w1row[kg + i * 32];
        {
            int f4 = tid, k = f4 >> 1, o4 = (f4 & 1) * 4;
            w2sT[o4 + 0][k] = v0.x; w2sT[o4 + 1][k] = v0.y;
            w2sT[o4 + 2][k] = v0.z; w2sT[o4 + 3][k] = v0.w;
            f4 = 256 + tid; k = f4 >> 1; o4 = (f4 & 1) * 4;
            w2sT[o4 + 0][k] = v1.x; w2sT[o4 + 1][k] = v1.y;
            w2sT[o4 + 2][k] = v1.z; w2sT[o4 + 3][k] = v1.w;
        }
        __syncthreads();
        float acc[8] = {0,0,0,0,0,0,0,0};
        #pragma unroll
        for (int i = 0; i < 8; ++i) {
            int k = kg + i * 32;
            #pragma unroll
            for (int o = 0; o < 8; ++o) acc[o] += w1v[i] * w2sT[o][k];
        }
        #pragma unroll
        for (int o = 0; o < 8; ++o) {
            acc[o] += __shfl_xor(acc[o], 1);
            acc[o] += __shfl_xor(acc[o], 2);
            acc[o] += __shfl_xor(acc[o], 4);
            acc[o] += __shfl_xor(acc[o], 8);
            acc[o] += __shfl_xor(acc[o], 16);
        }
        if (kg == 0) {
            const int kgf  = m >> 5;
            const int lhif = (m >> 3) & 3;
            const int j    = m & 7;
            #pragma unroll
            for (int o = 0; o < 8; ++o) {
                int c = e * 8 + o;
                int lanef = lhif * 16 + (c & 15);
                int F = (kgf * 4 + (c >> 4)) * 64 + lanef;
                wfP[(size_t)F * 8 + j] = bf16b(acc[o]);
            }
        }
    } else if (bid < 272) {
        const int b2i = bid - 256;
        const int kg = b2i >> 2, hi = b2i & 3;
        const int wv = tid >> 6, lane = tid & 63;
        const int l15 = lane & 15, lhi = lane >> 4;
        const int n  = wv * 64 + hi * 16 + l15;
        const int k0 = kg * 32 + lhi * 8;
        float w[8];
        #pragma unroll
        for (int j = 0; j < 8; ++j)
            w[j] = Ws[(size_t)(k0 + j) * 256 + n];
        uint4 u;
        u.x = pack2(w[0], w[1]); u.y = pack2(w[2], w[3]);
        u.z = pack2(w[4], w[5]); u.w = pack2(w[6], w[7]);
        wsP[((kg * 4 + hi) * 4 + wv) * 64 + lane] = u;
    } else {
        const int e = tid >> 5, l = tid & 31;
        float acc[8] = {0,0,0,0,0,0,0,0};
        #pragma unroll
        for (int i = 0; i < 8; ++i) {
            int k = l * 8 + i;
            float a = b1[e * 256 + k];
            const float* w2r = W2 + ((size_t)(e * 256 + k)) * 8;
            #pragma unroll
            for (int o = 0; o < 8; ++o) acc[o] += a * w2r[o];
        }
        #pragma unroll
        for (int o = 0; o < 8; ++o) {
            acc[o] += __shfl_xor(acc[o], 1);
            acc[o] += __shfl_xor(acc[o], 2);
            acc[o] += __shfl_xor(acc[o], 4);
            acc[o] += __shfl_xor(acc[o], 8);
            acc[o] += __shfl_xor(acc[o], 16);
        }
        if (l == 0) {
            #pragma unroll
            for (int o = 0; o < 8; ++o)
                bfuse[e * 8 + o] = acc[o] + b2[e * 8 + o];
        }
    }
}

// ---------------------------------------------------------------------------
// Fused v13: two 32-row tiles per block (rows bid*32 and (bid+1024)*32),
// grid=1024, weights REGISTER-RESIDENT across both tiles (wsA 64 + wfB 32
// VGPR; peak ~165 -> 3 waves/SIMD). LDS 24KB (xs+hs reused per tile).
// Tile-2 x staged after bar_B of tile-1 (xs reads done; hs untouched) --
// no cross-barrier register prefetch (r10 spill trap). 2 barriers/tile.
// Per-CU memory-path bytes: 4 blocks x (96K weights + 32K x) = 512KB
// (vs r16's ~900KB) -- the predicted -2us lever.
// ---------------------------------------------------------------------------
__global__ __launch_bounds__(256) void fused_kernel(
    const float* __restrict__ x,
    const int* __restrict__ phases,
    const float* __restrict__ bs,
    const uint4* __restrict__ wsP,
    const uint4* __restrict__ wfP,
    const float* __restrict__ bfuse,
    float* __restrict__ out) {
    __shared__ __align__(16) char lds[8192 + 16384];
    char* xs = lds;                      // [32][128] bf16, swz: addr ^= (row&7)<<4
    char* hs = lds + 8192;               // [32][256] bf16, swz: addr ^= (row&7)<<4

    const int tid = threadIdx.x;
    const int lane = tid & 63;
    const int wv = tid >> 6;
    const int l15 = lane & 15;
    const int lhi = lane >> 4;

    const float4* xg = (const float4*)x;

    // ---- issue tile-0 x loads ----
    float4 a0[2], d0[2];
    {
        int row0 = blockIdx.x * 32;
        #pragma unroll
        for (int it = 0; it < 2; ++it) {
            int c = it * 256 + tid;      // chunk of 8 floats; 512 chunks total
            int row = c >> 4, col8 = c & 15;
            int gi = (row0 + row) * 32 + col8 * 2;
            a0[it] = xg[gi]; d0[it] = xg[gi + 1];
        }
    }

    // ---- resident weights (one L2 pull per block, reused by both tiles) ----
    bf16x8 wsA[4][4];                    // A[n][k], n = wv*64+hi*16+l15
    #pragma unroll
    for (int hi = 0; hi < 4; ++hi)
        #pragma unroll
        for (int kg = 0; kg < 4; ++kg)
            wsA[hi][kg] = __builtin_bit_cast(bf16x8,
                wsP[((kg * 4 + hi) * 4 + wv) * 64 + lane]);
    bf16x8 wfB[8];                       // B[k][c], c = wv*16+l15
    #pragma unroll
    for (int kg = 0; kg < 8; ++kg)
        wfB[kg] = __builtin_bit_cast(bf16x8, wfP[(kg * 4 + wv) * 64 + lane]);

    // ---- small operands ----
    f32x4 bsv[4];
    #pragma unroll
    for (int hi = 0; hi < 4; ++hi)
        bsv[hi] = *(const f32x4*)(bs + wv * 64 + hi * 16 + lhi * 4);
    const float bfv = bfuse[wv * 16 + l15];
    const int myE = wv * 2 + (l15 >> 3);
    const int co  = l15 & 7;

    // ---- convert + write xs(t0) ----
    #pragma unroll
    for (int it = 0; it < 2; ++it) {
        int c = it * 256 + tid;
        int row = c >> 4, col8 = c & 15;
        unsigned addr = (unsigned)(row * 256 + col8 * 16);
        addr ^= (unsigned)((row & 7) << 4);
        uint4 u;
        u.x = pack2(a0[it].x, a0[it].y); u.y = pack2(a0[it].z, a0[it].w);
        u.z = pack2(d0[it].x, d0[it].y); u.w = pack2(d0[it].z, d0[it].w);
        *(uint4*)(xs + addr) = u;
    }

    #pragma unroll
    for (int t = 0; t < 2; ++t) {
        const int row0 = (blockIdx.x + t * 1024) * 32;
        __syncthreads();                 // bar_A: xs(t) ready; hs free (GEMM2(t-1) done)

        // ---- GEMM1: h^T[n][b] = WsT @ x^T (weights resident) ----
        f32x4 acc1[4][2];                // [hi][bi]
        #pragma unroll
        for (int hi = 0; hi < 4; ++hi)
            #pragma unroll
            for (int bi = 0; bi < 2; ++bi)
                acc1[hi][bi] = (f32x4){0.f, 0.f, 0.f, 0.f};
        #pragma unroll
        for (int kg = 0; kg < 4; ++kg) {
            bf16x8 xb[2];
            #pragma unroll
            for (int bi = 0; bi < 2; ++bi) {
                int b = bi * 16 + l15;
                unsigned addr = (unsigned)(b * 256 + (kg * 32 + lhi * 8) * 2);
                addr ^= (unsigned)((b & 7) << 4);
                xb[bi] = *(const bf16x8*)(xs + addr);
            }
            __builtin_amdgcn_s_setprio(1);
            #pragma unroll
            for (int hi = 0; hi < 4; ++hi)
                #pragma unroll
                for (int bi = 0; bi < 2; ++bi)
                    acc1[hi][bi] = __builtin_amdgcn_mfma_f32_16x16x32_bf16(
                        wsA[hi][kg], xb[bi], acc1[hi][bi], 0, 0, 0);
            __builtin_amdgcn_s_setprio(0);
        }

        // ---- routing loads (hidden under h-write + barrier) ----
        int ev[8];
        #pragma unroll
        for (int mi = 0; mi < 2; ++mi)
            #pragma unroll
            for (int r = 0; r < 4; ++r)
                ev[mi * 4 + r] = phases[row0 + mi * 16 + lhi * 4 + r];

        // ---- h-write: relu(acc1 + bs), conflict-free ds_write_b64 ----
        #pragma unroll
        for (int hi = 0; hi < 4; ++hi)
            #pragma unroll
            for (int bi = 0; bi < 2; ++bi) {
                float v0 = acc1[hi][bi][0] + bsv[hi][0]; v0 = v0 > 0.f ? v0 : 0.f;
                float v1 = acc1[hi][bi][1] + bsv[hi][1]; v1 = v1 > 0.f ? v1 : 0.f;
                float v2 = acc1[hi][bi][2] + bsv[hi][2]; v2 = v2 > 0.f ? v2 : 0.f;
                float v3 = acc1[hi][bi][3] + bsv[hi][3]; v3 = v3 > 0.f ? v3 : 0.f;
                uint2 u; u.x = pack2(v0, v1); u.y = pack2(v2, v3);
                int b = bi * 16 + l15;
                int n0 = wv * 64 + hi * 16 + lhi * 4;
                unsigned addr = (unsigned)(b * 512 + n0 * 2);
                addr ^= (unsigned)((b & 7) << 4);
                *(uint2*)(hs + addr) = u;
            }
        __syncthreads();                 // bar_B: hs ready; xs(t) reads done

        // ---- stage xs(t+1): overlaps GEMM2(t) (xs free since bar_B) ----
        if (t == 0) {
            float4 a1[2], d1[2];
            int nrow0 = (blockIdx.x + 1024) * 32;
            #pragma unroll
            for (int it = 0; it < 2; ++it) {
                int c = it * 256 + tid;
                int row = c >> 4, col8 = c & 15;
                int gi = (nrow0 + row) * 32 + col8 * 2;
                a1[it] = xg[gi]; d1[it] = xg[gi + 1];
            }
            #pragma unroll
            for (int it = 0; it < 2; ++it) {
                int c = it * 256 + tid;
                int row = c >> 4, col8 = c & 15;
                unsigned addr = (unsigned)(row * 256 + col8 * 16);
                addr ^= (unsigned)((row & 7) << 4);
                uint4 u;
                u.x = pack2(a1[it].x, a1[it].y); u.y = pack2(a1[it].z, a1[it].w);
                u.z = pack2(d1[it].x, d1[it].y); u.w = pack2(d1[it].z, d1[it].w);
                *(uint4*)(xs + addr) = u;
            }
        }

        // ---- GEMM2: y[b][c] = h @ WfT + bfuse (weights resident) ----
        f32x4 acc2[2];
        #pragma unroll
        for (int mi = 0; mi < 2; ++mi)
            acc2[mi] = (f32x4){bfv, bfv, bfv, bfv};
        #pragma unroll
        for (int kg = 0; kg < 8; ++kg) {
            bf16x8 ha[2];
            #pragma unroll
            for (int mi = 0; mi < 2; ++mi) {
                int b = mi * 16 + l15;
                unsigned addr = (unsigned)(b * 512 + (kg * 32 + lhi * 8) * 2);
                addr ^= (unsigned)((b & 7) << 4);
                ha[mi] = *(const bf16x8*)(hs + addr);
            }
            __builtin_amdgcn_s_setprio(1);
            #pragma unroll
            for (int mi = 0; mi < 2; ++mi)
                acc2[mi] = __builtin_amdgcn_mfma_f32_16x16x32_bf16(
                    ha[mi], wfB[kg], acc2[mi], 0, 0, 0);
            __builtin_amdgcn_s_setprio(0);
        }

        // ---- routed predicated stores ----
        #pragma unroll
        for (int mi = 0; mi < 2; ++mi)
            #pragma unroll
            for (int r = 0; r < 4; ++r) {
                int b = mi * 16 + lhi * 4 + r;
                if (ev[mi * 4 + r] == myE)
                    out[(size_t)(row0 + b) * 8 + co] = acc2[mi][r];
            }
    }
}

extern "C" void kernel_launch(void* const* d_in, const int* in_sizes, int n_in,
                              void* d_out, int out_size, void* d_ws, size_t ws_size,
                              hipStream_t stream) {
    const float* x      = (const float*)d_in[0];
    const int*   phases = (const int*)d_in[1];
    const float* Ws     = (const float*)d_in[2];
    const float* bs     = (const float*)d_in[3];
    const float* W1     = (const float*)d_in[4];
    const float* b1     = (const float*)d_in[5];
    const float* W2     = (const float*)d_in[6];
    const float* b2     = (const float*)d_in[7];
    float* out = (float*)d_out;

    uint4*          wsP   = (uint4*)d_ws;
    unsigned short* wfP   = (unsigned short*)((char*)d_ws + 65536);
    float*          bfuse = (float*)((char*)d_ws + 98304);

    prep_kernel<<<273, 256, 0, stream>>>(Ws, b1, W1, W2, b2,
                                         wsP, wfP, bfuse);
    fused_kernel<<<1024, 256, 0, stream>>>(
        x, phases, bs, wsP, (const uint4*)wfP, bfuse, out);
}

// Round 18
// 22.509 us; speedup vs baseline: 1.0469x; 1.0469x over previous
//
#include <hip/hip_runtime.h>
#include <hip/hip_bf16.h>
#include <cstdint>

// B=65536, D=128, H=256, O=8, E=8
// Algebra: no activation between head Linears -> y = h @ (W1 W2) + (b1 W2 + b2).
// Budget (r14/r15): harness floor ~6.7us | prep+launch ~3.9 | fused+launch ~12.1.
// r18 = r16 (best, 22.67us) + T1 XCD-aware blockIdx swizzle on fused:
// consecutive swizzled blocks land on the SAME XCD -> per-XCD L2 keeps the
// 96KB weight stream hot and x streams as one contiguous slice per XCD.
// nwg=2048 % 8 == 0 -> simple bijective swizzle. Math byte-identical to r16.
// ws layout (weights pre-packed in MFMA FRAGMENT ORDER for coalesced loads):
//   wsP  uint4[4096]  @0      (64KB): wsP[((kg*4+hi)*4+wv)*64+lane] = A-frag of Ws^T
//   wfP  uint4[2048]  @65536  (32KB): wfP[(kg*4+wv)*64+lane]        = B-frag of (W1@W2)^T
//   bfuse f32[64]     @98304:          bfuse[e*8+o] = (b1[e]@W2[e])[o] + b2[e][o]

using bf16x8 = __attribute__((ext_vector_type(8))) __bf16;
using f32x4  = __attribute__((ext_vector_type(4))) float;

__device__ __forceinline__ unsigned short bf16b(float f) {
    __bf16 h = (__bf16)f;                       // RNE; pairs fuse to v_cvt_pk_bf16_f32
    return __builtin_bit_cast(unsigned short, h);
}
__device__ __forceinline__ unsigned pack2(float a, float b) {
    return (unsigned)bf16b(a) | ((unsigned)bf16b(b) << 16);
}

// ---------------------------------------------------------------------------
// Prep v5 (validated r9-r17): 273 blocks.
// ---------------------------------------------------------------------------
__global__ void prep_kernel(const float* __restrict__ Ws,
                            const float* __restrict__ b1,
                            const float* __restrict__ W1,
                            const float* __restrict__ W2,
                            const float* __restrict__ b2,
                            uint4* __restrict__ wsP,
                            unsigned short* __restrict__ wfP,
                            float* __restrict__ bfuse) {
    const int bid = blockIdx.x, tid = threadIdx.x;
    if (bid < 256) {
        __shared__ float w2sT[8][256];               // W2[e]^T : [o][k]
        const int e = bid >> 5, mc = bid & 31;
        const float* W2e = W2 + (size_t)e * 2048;
        float4 v0 = ((const float4*)W2e)[tid];
        float4 v1 = ((const float4*)W2e)[256 + tid];
        const int mloc = tid >> 5, kg = tid & 31;    // k = kg + i*32
        const int m = mc * 8 + mloc;
        const float* w1row = W1 + ((size_t)e * 256 + m) * 256;
        float w1v[8];
        #pragma unroll
        for (int i = 0; i < 8; ++i) w1v[i] = w1row[kg + i * 32];
        {
            int f4 = tid, k = f4 >> 1, o4 = (f4 & 1) * 4;
            w2sT[o4 + 0][k] = v0.x; w2sT[o4 + 1][k] = v0.y;
            w2sT[o4 + 2][k] = v0.z; w2sT[o4 + 3][k] = v0.w;
            f4 = 256 + tid; k = f4 >> 1; o4 = (f4 & 1) * 4;
            w2sT[o4 + 0][k] = v1.x; w2sT[o4 + 1][k] = v1.y;
            w2sT[o4 + 2][k] = v1.z; w2sT[o4 + 3][k] = v1.w;
        }
        __syncthreads();
        float acc[8] = {0,0,0,0,0,0,0,0};
        #pragma unroll
        for (int i = 0; i < 8; ++i) {
            int k = kg + i * 32;
            #pragma unroll
            for (int o = 0; o < 8; ++o) acc[o] += w1v[i] * w2sT[o][k];
        }
        #pragma unroll
        for (int o = 0; o < 8; ++o) {
            acc[o] += __shfl_xor(acc[o], 1);
            acc[o] += __shfl_xor(acc[o], 2);
            acc[o] += __shfl_xor(acc[o], 4);
            acc[o] += __shfl_xor(acc[o], 8);
            acc[o] += __shfl_xor(acc[o], 16);
        }
        if (kg == 0) {
            const int kgf  = m >> 5;
            const int lhif = (m >> 3) & 3;
            const int j    = m & 7;
            #pragma unroll
            for (int o = 0; o < 8; ++o) {
                int c = e * 8 + o;
                int lanef = lhif * 16 + (c & 15);
                int F = (kgf * 4 + (c >> 4)) * 64 + lanef;
                wfP[(size_t)F * 8 + j] = bf16b(acc[o]);
            }
        }
    } else if (bid < 272) {
        const int b2i = bid - 256;
        const int kg = b2i >> 2, hi = b2i & 3;
        const int wv = tid >> 6, lane = tid & 63;
        const int l15 = lane & 15, lhi = lane >> 4;
        const int n  = wv * 64 + hi * 16 + l15;
        const int k0 = kg * 32 + lhi * 8;
        float w[8];
        #pragma unroll
        for (int j = 0; j < 8; ++j)
            w[j] = Ws[(size_t)(k0 + j) * 256 + n];
        uint4 u;
        u.x = pack2(w[0], w[1]); u.y = pack2(w[2], w[3]);
        u.z = pack2(w[4], w[5]); u.w = pack2(w[6], w[7]);
        wsP[((kg * 4 + hi) * 4 + wv) * 64 + lane] = u;
    } else {
        const int e = tid >> 5, l = tid & 31;
        float acc[8] = {0,0,0,0,0,0,0,0};
        #pragma unroll
        for (int i = 0; i < 8; ++i) {
            int k = l * 8 + i;
            float a = b1[e * 256 + k];
            const float* w2r = W2 + ((size_t)(e * 256 + k)) * 8;
            #pragma unroll
            for (int o = 0; o < 8; ++o) acc[o] += a * w2r[o];
        }
        #pragma unroll
        for (int o = 0; o < 8; ++o) {
            acc[o] += __shfl_xor(acc[o], 1);
            acc[o] += __shfl_xor(acc[o], 2);
            acc[o] += __shfl_xor(acc[o], 4);
            acc[o] += __shfl_xor(acc[o], 8);
            acc[o] += __shfl_xor(acc[o], 16);
        }
        if (l == 0) {
            #pragma unroll
            for (int o = 0; o < 8; ++o)
                bfuse[e * 8 + o] = acc[o] + b2[e * 8 + o];
        }
    }
}

// ---------------------------------------------------------------------------
// Fused v14: r16 kernel (32-row tiles, grid=2048, LDS 24KB, wsA streamed
// 1-deep, ev deferred) + XCD-aware blockIdx swizzle (T1). Round-robin
// dispatch puts original bid on XCD bid%8; remap so XCD k owns contiguous
// tiles k*256..k*256+255 (one 4MB x slice + hot 96KB weights per XCD L2).
// ---------------------------------------------------------------------------
__global__ __launch_bounds__(256) void fused_kernel(
    const float* __restrict__ x,
    const int* __restrict__ phases,
    const float* __restrict__ bs,
    const uint4* __restrict__ wsP,
    const uint4* __restrict__ wfP,
    const float* __restrict__ bfuse,
    float* __restrict__ out) {
    __shared__ __align__(16) char lds[8192 + 16384];
    char* xs = lds;                      // [32][128] bf16, swz: addr ^= (row&7)<<4
    char* hs = lds + 8192;               // [32][256] bf16, swz: addr ^= (row&7)<<4

    const int tid = threadIdx.x;
    const int lane = tid & 63;
    const int wv = tid >> 6;
    const int l15 = lane & 15;
    const int lhi = lane >> 4;
    // T1: bijective XCD swizzle (nwg=2048, 2048/8=256 per XCD)
    const int bid = (blockIdx.x & 7) * 256 + (blockIdx.x >> 3);
    const int row0 = bid * 32;

    const float4* xg = (const float4*)x;

    // ---- issue x loads (one 16KB tile, cooperative) ----
    float4 a0[2], d0[2];
    #pragma unroll
    for (int it = 0; it < 2; ++it) {
        int c = it * 256 + tid;          // chunk of 8 floats; 512 chunks total
        int row = c >> 4, col8 = c & 15;
        int gi = (row0 + row) * 32 + col8 * 2;
        a0[it] = xg[gi]; d0[it] = xg[gi + 1];
    }

    // ---- small operands needed right after GEMM1 ----
    f32x4 bsv[4];
    #pragma unroll
    for (int hi = 0; hi < 4; ++hi)
        bsv[hi] = *(const f32x4*)(bs + wv * 64 + hi * 16 + lhi * 4);
    const float bfv = bfuse[wv * 16 + l15];
    const int myE = wv * 2 + (l15 >> 3);
    const int co  = l15 & 7;

    // ---- convert + write xs ----
    #pragma unroll
    for (int it = 0; it < 2; ++it) {
        int c = it * 256 + tid;
        int row = c >> 4, col8 = c & 15;
        unsigned addr = (unsigned)(row * 256 + col8 * 16);
        addr ^= (unsigned)((row & 7) << 4);
        uint4 u;
        u.x = pack2(a0[it].x, a0[it].y); u.y = pack2(a0[it].z, a0[it].w);
        u.z = pack2(d0[it].x, d0[it].y); u.w = pack2(d0[it].z, d0[it].w);
        *(uint4*)(xs + addr) = u;
    }

    // ---- first wsA group (in flight across the barrier) ----
    bf16x8 wsCur[4];
    #pragma unroll
    for (int hi = 0; hi < 4; ++hi)
        wsCur[hi] = __builtin_bit_cast(bf16x8, wsP[(hi * 4 + wv) * 64 + lane]);

    __syncthreads();                     // xs ready

    // ---- GEMM1: h^T[n][b] = WsT @ x^T, wsA streamed 1-deep ----
    f32x4 acc1[4][2];                    // [hi][bi]
    #pragma unroll
    for (int hi = 0; hi < 4; ++hi)
        #pragma unroll
        for (int bi = 0; bi < 2; ++bi)
            acc1[hi][bi] = (f32x4){0.f, 0.f, 0.f, 0.f};
    #pragma unroll
    for (int kg = 0; kg < 4; ++kg) {
        bf16x8 wsNxt[4];
        if (kg < 3) {
            #pragma unroll
            for (int hi = 0; hi < 4; ++hi)
                wsNxt[hi] = __builtin_bit_cast(bf16x8,
                    wsP[(((kg + 1) * 4 + hi) * 4 + wv) * 64 + lane]);
        }
        bf16x8 xb[2];
        #pragma unroll
        for (int bi = 0; bi < 2; ++bi) {
            int b = bi * 16 + l15;
            unsigned addr = (unsigned)(b * 256 + (kg * 32 + lhi * 8) * 2);
            addr ^= (unsigned)((b & 7) << 4);
            xb[bi] = *(const bf16x8*)(xs + addr);
        }
        __builtin_amdgcn_s_setprio(1);
        #pragma unroll
        for (int hi = 0; hi < 4; ++hi)
            #pragma unroll
            for (int bi = 0; bi < 2; ++bi)
                acc1[hi][bi] = __builtin_amdgcn_mfma_f32_16x16x32_bf16(
                    wsCur[hi], xb[bi], acc1[hi][bi], 0, 0, 0);
        __builtin_amdgcn_s_setprio(0);
        if (kg < 3) {
            #pragma unroll
            for (int hi = 0; hi < 4; ++hi) wsCur[hi] = wsNxt[hi];
        }
    }

    // ---- issue wfB + routing loads (hidden under h-write + barrier) ----
    bf16x8 wfB[8];                       // B[k][c], c = wv*16+l15
    #pragma unroll
    for (int kg = 0; kg < 8; ++kg)
        wfB[kg] = __builtin_bit_cast(bf16x8, wfP[(kg * 4 + wv) * 64 + lane]);
    int ev[8];
    #pragma unroll
    for (int mi = 0; mi < 2; ++mi)
        #pragma unroll
        for (int r = 0; r < 4; ++r)
            ev[mi * 4 + r] = phases[row0 + mi * 16 + lhi * 4 + r];

    // ---- h-write: relu(acc1 + bs), conflict-free ds_write_b64 ----
    #pragma unroll
    for (int hi = 0; hi < 4; ++hi)
        #pragma unroll
        for (int bi = 0; bi < 2; ++bi) {
            float v0 = acc1[hi][bi][0] + bsv[hi][0]; v0 = v0 > 0.f ? v0 : 0.f;
            float v1 = acc1[hi][bi][1] + bsv[hi][1]; v1 = v1 > 0.f ? v1 : 0.f;
            float v2 = acc1[hi][bi][2] + bsv[hi][2]; v2 = v2 > 0.f ? v2 : 0.f;
            float v3 = acc1[hi][bi][3] + bsv[hi][3]; v3 = v3 > 0.f ? v3 : 0.f;
            uint2 u; u.x = pack2(v0, v1); u.y = pack2(v2, v3);
            int b = bi * 16 + l15;
            int n0 = wv * 64 + hi * 16 + lhi * 4;
            unsigned addr = (unsigned)(b * 512 + n0 * 2);
            addr ^= (unsigned)((b & 7) << 4);
            *(uint2*)(hs + addr) = u;
        }
    __syncthreads();                     // hs ready

    // ---- GEMM2: y[b][c] = h @ WfT + bfuse ----
    f32x4 acc2[2];
    #pragma unroll
    for (int mi = 0; mi < 2; ++mi)
        acc2[mi] = (f32x4){bfv, bfv, bfv, bfv};
    #pragma unroll
    for (int kg = 0; kg < 8; ++kg) {
        bf16x8 ha[2];
        #pragma unroll
        for (int mi = 0; mi < 2; ++mi) {
            int b = mi * 16 + l15;
            unsigned addr = (unsigned)(b * 512 + (kg * 32 + lhi * 8) * 2);
            addr ^= (unsigned)((b & 7) << 4);
            ha[mi] = *(const bf16x8*)(hs + addr);
        }
        __builtin_amdgcn_s_setprio(1);
        #pragma unroll
        for (int mi = 0; mi < 2; ++mi)
            acc2[mi] = __builtin_amdgcn_mfma_f32_16x16x32_bf16(
                ha[mi], wfB[kg], acc2[mi], 0, 0, 0);
        __builtin_amdgcn_s_setprio(0);
    }

    // ---- routed predicated stores (ev preloaded) ----
    #pragma unroll
    for (int mi = 0; mi < 2; ++mi)
        #pragma unroll
        for (int r = 0; r < 4; ++r) {
            int b = mi * 16 + lhi * 4 + r;
            if (ev[mi * 4 + r] == myE)
                out[(size_t)(row0 + b) * 8 + co] = acc2[mi][r];
        }
}

extern "C" void kernel_launch(void* const* d_in, const int* in_sizes, int n_in,
                              void* d_out, int out_size, void* d_ws, size_t ws_size,
                              hipStream_t stream) {
    const float* x      = (const float*)d_in[0];
    const int*   phases = (const int*)d_in[1];
    const float* Ws     = (const float*)d_in[2];
    const float* bs     = (const float*)d_in[3];
    const float* W1     = (const float*)d_in[4];
    const float* b1     = (const float*)d_in[5];
    const float* W2     = (const float*)d_in[6];
    const float* b2     = (const float*)d_in[7];
    float* out = (float*)d_out;

    uint4*          wsP   = (uint4*)d_ws;
    unsigned short* wfP   = (unsigned short*)((char*)d_ws + 65536);
    float*          bfuse = (float*)((char*)d_ws + 98304);

    prep_kernel<<<273, 256, 0, stream>>>(Ws, b1, W1, W2, b2,
                                         wsP, wfP, bfuse);
    fused_kernel<<<2048, 256, 0, stream>>>(
        x, phases, bs, wsP, (const uint4*)wfP, bfuse, out);
}